// Round 15
// baseline (74.451 us; speedup 1.0000x reference)
//
#include <hip/hip_runtime.h>
#include <hip/hip_fp16.h>

#define B_  64
#define L_  512
#define D_  768
#define S_  64
#define M_  4096
#define N1_ 384
#define N2_ 128
#define SEG_C 4
#define NMB (M_ / SEG_C)      // 1024 mean blocks
#define NW1 24                // W1 swizzle blocks (16 cols each)
#define NW2 8                 // W2 swizzle blocks

typedef __attribute__((ext_vector_type(8))) _Float16 half8;
typedef __attribute__((ext_vector_type(8))) short short8v;
typedef __attribute__((ext_vector_type(4))) float f32x4;

__device__ __forceinline__ ushort f2h(float x) {
  return __half_as_ushort(__float2half_rn(x));
}

// ---------------------------------------------------------------------------
// Kernel 1 (unchanged from R14): streaming segment-mean + weight swizzle.
// ---------------------------------------------------------------------------
__global__ __launch_bounds__(192) void mean_prep_kernel(
    const float* __restrict__ hidden, const int* __restrict__ seg_ids,
    ushort* __restrict__ means,
    const float* __restrict__ W1, ushort* __restrict__ w1s,
    const float* __restrict__ W2, ushort* __restrict__ w2s) {
  const int bid = blockIdx.x;
  const int tid = threadIdx.x;

  if (bid < NMB) {
    const int b  = bid >> 4;
    const int s0 = (bid & 15) * SEG_C;
    __shared__ int sids[L_];
    __shared__ int wred[3];
    int pk = 0;
    if (tid < 128) {
      int4 v = ((const int4*)(seg_ids + b * L_))[tid];
      ((int4*)sids)[tid] = v;
      int clo = (v.x < s0) + (v.y < s0) + (v.z < s0) + (v.w < s0);
      int chi = (v.x < s0 + SEG_C) + (v.y < s0 + SEG_C) +
                (v.z < s0 + SEG_C) + (v.w < s0 + SEG_C);
      pk = clo * 1024 + chi;
    }
    #pragma unroll
    for (int off = 1; off < 64; off <<= 1) pk += __shfl_xor(pk, off);
    if ((tid & 63) == 0) wred[tid >> 6] = pk;
    __syncthreads();
    const int tot = wred[0] + wred[1] + wred[2];
    const int lo = tot >> 10;
    const int hi = tot & 1023;

    const float4* hp = (const float4*)(hidden + (size_t)b * L_ * D_) + tid;
    ushort* outb = means + (size_t)b * S_ * D_ + tid * 4;
    const uint2 zz = {0u, 0u};

    int cur = (lo < hi) ? sids[lo] : s0 + SEG_C;
    for (int z = s0; z < cur; ++z)
      *(uint2*)(outb + (size_t)z * D_) = zz;

    float4 acc = {0.0f, 0.0f, 0.0f, 0.0f};
    int segstart = lo;
    for (int l = lo; l < hi; l += 8) {
      float4 v[8];
      int sv[8];
      #pragma unroll
      for (int k = 0; k < 8; ++k) {
        v[k]  = hp[(size_t)min(l + k, hi - 1) * (D_ / 4)];
        sv[k] = sids[min(l + k + 1, hi - 1)];
      }
      #pragma unroll
      for (int k = 0; k < 8; ++k) {
        if (l + k < hi) {
          acc.x += v[k].x; acc.y += v[k].y;
          acc.z += v[k].z; acc.w += v[k].w;
          const int nx = l + k + 1;
          if (nx == hi || sv[k] != cur) {
            const float inv = 1.0f / (float)(nx - segstart);
            ushort4 h;
            h.x = f2h(acc.x * inv); h.y = f2h(acc.y * inv);
            h.z = f2h(acc.z * inv); h.w = f2h(acc.w * inv);
            *(ushort4*)(outb + (size_t)cur * D_) = h;
            const int nxt = (nx == hi) ? s0 + SEG_C : sv[k];
            for (int z = cur + 1; z < nxt; ++z)
              *(uint2*)(outb + (size_t)z * D_) = zz;
            acc.x = 0.0f; acc.y = 0.0f; acc.z = 0.0f; acc.w = 0.0f;
            segstart = nx; cur = nxt;
          }
        }
      }
    }
  } else if (bid < NMB + NW1) {
    const int wb = bid - NMB;
    const int n0 = wb * 16;
    #pragma unroll 1
    for (int i = 0; i < 8; ++i) {
      const int slot = i * 192 + tid;          // 0..1535
      const int kt = slot >> 6, l = slot & 63;
      short8v r;
      #pragma unroll
      for (int e = 0; e < 8; ++e) {
        float x = W1[(size_t)(kt * 32 + ((l >> 4) << 3) + e) * N1_ + n0 + (l & 15)];
        r[e] = (short)f2h(x);
      }
      *(short8v*)(w1s + ((size_t)wb * 1536 + slot) * 8) = r;
    }
  } else {
    const int wb = bid - NMB - NW1;
    const int n0 = wb * 16;
    #pragma unroll 1
    for (int i = 0; i < 4; ++i) {
      const int slot = i * 192 + tid;          // 0..767
      const int kt = slot >> 6, l = slot & 63;
      short8v r;
      #pragma unroll
      for (int e = 0; e < 8; ++e) {
        float x = W2[(size_t)(kt * 32 + ((l >> 4) << 3) + e) * N2_ + n0 + (l & 15)];
        r[e] = (short)f2h(x);
      }
      *(short8v*)(w2s + ((size_t)wb * 768 + slot) * 8) = r;
    }
  }
}

// ---------------------------------------------------------------------------
// Kernel 2 (unchanged from R14): fused MLP per quarter-sample.
// R15 probe: launched 5x (idempotent overwrite of out) — Δ vs R14's 36.07us
// equals 4x one warm mlp_q pass.
// ---------------------------------------------------------------------------
__global__ __launch_bounds__(512, 1) void mlp_q(
    const ushort* __restrict__ means, const ushort* __restrict__ w1s,
    const float* __restrict__ b1, const ushort* __restrict__ w2s,
    const float* __restrict__ b2, const float* __restrict__ W3,
    const float* __restrict__ b3, float* __restrict__ out) {
  __shared__ __align__(16) char lds[37504];
  ushort* sM = (ushort*)lds;                 // [16][776]
  ushort* sH = (ushort*)(lds + 24832);       // [16][392]
  float*  pl = (float*)(lds + 37376);        // 32 floats
  const int tid  = threadIdx.x;
  const int wid  = tid >> 6;
  const int lane = tid & 63;
  const int lrow = lane & 15;
  const int lk   = (lane >> 4) * 8;
  const int b    = blockIdx.x >> 2;
  const int qs   = blockIdx.x & 3;
  const int row0 = b * 64 + qs * 16;

  {
    const ushort* src = means + (size_t)row0 * D_;
    #pragma unroll
    for (int i = 0; i < 3; ++i) {
      const int g = tid + 512 * i;
      const int r = g / 96, c8 = g % 96;
      *(uint4*)(sM + r * 776 + c8 * 8) = *(const uint4*)(src + r * 768 + c8 * 8);
    }
  }
  if (tid < 32) pl[tid] = 0.0f;
  __syncthreads();

  f32x4 acc[3] = {};
  {
    const ushort* bp = w1s + (size_t)(3 * wid) * 24 * 512 + lane * 8;
    #pragma unroll 4
    for (int kt = 0; kt < 24; ++kt) {
      half8 af = *(const half8*)&sM[lrow * 776 + kt * 32 + lk];
      half8 bf[3];
      #pragma unroll
      for (int j = 0; j < 3; ++j)
        bf[j] = *(const half8*)(bp + ((size_t)j * 24 + kt) * 512);
      #pragma unroll
      for (int j = 0; j < 3; ++j)
        acc[j] = __builtin_amdgcn_mfma_f32_16x16x32_f16(af, bf[j], acc[j], 0, 0, 0);
    }
  }
  #pragma unroll
  for (int j = 0; j < 3; ++j) {
    const int n = (3 * wid + j) * 16 + lrow;
    const float bj = b1[n];
    #pragma unroll
    for (int r = 0; r < 4; ++r) {
      const int m = (lane >> 4) * 4 + r;
      sH[m * 392 + n] = f2h(fmaxf(acc[j][r] + bj, 0.0f));
    }
  }
  __syncthreads();

  f32x4 a2 = {};
  {
    const ushort* bp = w2s + (size_t)wid * 12 * 512 + lane * 8;
    #pragma unroll 4
    for (int kt = 0; kt < 12; ++kt) {
      half8 af = *(const half8*)&sH[lrow * 392 + kt * 32 + lk];
      half8 bf = *(const half8*)(bp + (size_t)kt * 512);
      a2 = __builtin_amdgcn_mfma_f32_16x16x32_f16(af, bf, a2, 0, 0, 0);
    }
  }

  const int col = wid * 16 + lrow;
  const float w30 = W3[col * 2 + 0];
  const float w31 = W3[col * 2 + 1];
  const float b2v = b2[col];
  #pragma unroll
  for (int r = 0; r < 4; ++r) {
    float v = fmaxf(a2[r] + b2v, 0.0f);
    float p0 = v * w30;
    float p1 = v * w31;
    p0 += __shfl_xor(p0, 1); p1 += __shfl_xor(p1, 1);
    p0 += __shfl_xor(p0, 2); p1 += __shfl_xor(p1, 2);
    p0 += __shfl_xor(p0, 4); p1 += __shfl_xor(p1, 4);
    p0 += __shfl_xor(p0, 8); p1 += __shfl_xor(p1, 8);
    if (lrow == 0) {
      const int row = (lane >> 4) * 4 + r;
      atomicAdd(&pl[row * 2 + 0], p0);
      atomicAdd(&pl[row * 2 + 1], p1);
    }
  }
  __syncthreads();
  if (tid < 32) {
    const int row = tid >> 1, c = tid & 1;
    out[(size_t)(row0 + row) * 2 + c] = pl[tid] + b3[c];
  }
}

// ---------------------------------------------------------------------------
extern "C" void kernel_launch(void* const* d_in, const int* in_sizes, int n_in,
                              void* d_out, int out_size, void* d_ws, size_t ws_size,
                              hipStream_t stream) {
  const float* hidden  = (const float*)d_in[0];
  const int*   seg_ids = (const int*)d_in[1];
  const float* W1 = (const float*)d_in[2];
  const float* b1 = (const float*)d_in[3];
  const float* W2 = (const float*)d_in[4];
  const float* b2 = (const float*)d_in[5];
  const float* W3 = (const float*)d_in[6];
  const float* b3 = (const float*)d_in[7];
  float* out = (float*)d_out;

  char* p = (char*)d_ws;
  ushort* means = (ushort*)p;  p += (size_t)M_ * D_ * 2;
  ushort* w1s   = (ushort*)p;  p += (size_t)N1_ * D_ * 2;
  ushort* w2s   = (ushort*)p;  p += (size_t)N2_ * N1_ * 2;

  mean_prep_kernel<<<NMB + NW1 + NW2, 192, 0, stream>>>(
      hidden, seg_ids, means, W1, w1s, W2, w2s);
  // R15 probe: 5x mlp_q (idempotent). Δ vs R14 = 4x one warm pass.
  mlp_q<<<B_ * 4, 512, 0, stream>>>(means, w1s, b1, w2s, b2, W3, b3, out);
  mlp_q<<<B_ * 4, 512, 0, stream>>>(means, w1s, b1, w2s, b2, W3, b3, out);
  mlp_q<<<B_ * 4, 512, 0, stream>>>(means, w1s, b1, w2s, b2, W3, b3, out);
  mlp_q<<<B_ * 4, 512, 0, stream>>>(means, w1s, b1, w2s, b2, W3, b3, out);
  mlp_q<<<B_ * 4, 512, 0, stream>>>(means, w1s, b1, w2s, b2, W3, b3, out);
}

// Round 16
// 34.838 us; speedup vs baseline: 2.1371x; 2.1371x over previous
//
#include <hip/hip_runtime.h>
#include <hip/hip_fp16.h>

#define B_  64
#define L_  512
#define D_  768
#define S_  64
#define N1_ 384
#define N2_ 128

typedef __attribute__((ext_vector_type(8))) _Float16 half8;
typedef __attribute__((ext_vector_type(8))) short short8v;
typedef __attribute__((ext_vector_type(4))) float f32x4;

__device__ __forceinline__ ushort f2h(float x) {
  return __half_as_ushort(__float2half_rn(x));
}

// ---------------------------------------------------------------------------
// Kernel A: weight swizzle to MFMA B-fragment lane order (proven R13/R14).
// blob(ntile,kt)[lane][e] = W[kt*32+(lane>>4)*8+e][ntile*16+(lane&15)].
// Blocks 0..23 -> W1 ntiles; 24..31 -> W2 ntiles.
// ---------------------------------------------------------------------------
__global__ __launch_bounds__(192) void wswz_kernel(
    const float* __restrict__ W1, ushort* __restrict__ w1s,
    const float* __restrict__ W2, ushort* __restrict__ w2s) {
  const int bid = blockIdx.x;
  const int tid = threadIdx.x;
  if (bid < 24) {
    const int n0 = bid * 16;
    #pragma unroll 1
    for (int i = 0; i < 8; ++i) {
      const int slot = i * 192 + tid;          // 0..1535
      const int kt = slot >> 6, l = slot & 63;
      short8v r;
      #pragma unroll
      for (int e = 0; e < 8; ++e) {
        float x = W1[(size_t)(kt * 32 + ((l >> 4) << 3) + e) * N1_ + n0 + (l & 15)];
        r[e] = (short)f2h(x);
      }
      *(short8v*)(w1s + ((size_t)bid * 1536 + slot) * 8) = r;
    }
  } else {
    const int wb = bid - 24;
    const int n0 = wb * 16;
    #pragma unroll 1
    for (int i = 0; i < 4; ++i) {
      const int slot = i * 192 + tid;          // 0..767
      const int kt = slot >> 6, l = slot & 63;
      short8v r;
      #pragma unroll
      for (int e = 0; e < 8; ++e) {
        float x = W2[(size_t)(kt * 32 + ((l >> 4) << 3) + e) * N2_ + n0 + (l & 15)];
        r[e] = (short)f2h(x);
      }
      *(short8v*)(w2s + ((size_t)wb * 768 + slot) * 8) = r;
    }
  }
}

// ---------------------------------------------------------------------------
// Kernel B: FULLY fused mean+MLP per quarter-sample. 256 blocks x 512 thr.
//  1. seg_ids of sample -> LDS (2 KB).
//  2. Two independent 192-thread groups each stream 8 segments' contiguous
//     token span (R9-proven masked-batch boundary-flush) writing f16 means
//     DIRECTLY into LDS sM[16][776] — means never touch HBM.
//  3. MLP phase1 (24 barrier-free k-tiles, B-frags coalesced from L2-hot
//     swizzled w1s), h1 -> LDS, phase2 + W3 shfl-reduce epilogue -> out.
// ---------------------------------------------------------------------------
__global__ __launch_bounds__(512, 1) void fused_all(
    const float* __restrict__ hidden, const int* __restrict__ seg_ids,
    const ushort* __restrict__ w1s, const float* __restrict__ b1,
    const ushort* __restrict__ w2s, const float* __restrict__ b2,
    const float* __restrict__ W3, const float* __restrict__ b3,
    float* __restrict__ out) {
  __shared__ __align__(16) char lds[39584];
  int*    sids = (int*)lds;                     // 2048 B
  ushort* sM   = (ushort*)(lds + 2048);         // [16][776] = 24832 B
  ushort* sH   = (ushort*)(lds + 26880);        // [16][392] = 12544 B
  float*  pl   = (float*)(lds + 39424);         // 32 floats
  int*    wred = (int*)(lds + 39552);           // 4 ints

  const int tid  = threadIdx.x;
  const int wid  = tid >> 6;
  const int lane = tid & 63;
  const int lrow = lane & 15;
  const int lk   = (lane >> 4) * 8;
  const int b    = blockIdx.x >> 2;
  const int qs   = blockIdx.x & 3;
  const int s0   = qs * 16;
  const int row0 = b * 64 + s0;

  if (tid < 128)
    ((int4*)sids)[tid] = ((const int4*)(seg_ids + b * L_))[tid];
  if (tid < 32) pl[tid] = 0.0f;
  __syncthreads();

  // ---- bounds per 8-segment group (g=0,1; threads 384..511 idle) ----
  const int g  = tid / 192;
  const int gt = tid - g * 192;
  if (g < 2) {
    const int s0g = s0 + g * 8;
    int pk = 0;
    if (gt < 128) {
      int4 v = ((const int4*)sids)[gt];
      int clo = (v.x < s0g) + (v.y < s0g) + (v.z < s0g) + (v.w < s0g);
      int chi = (v.x < s0g + 8) + (v.y < s0g + 8) +
                (v.z < s0g + 8) + (v.w < s0g + 8);
      pk = clo * 1024 + chi;
    }
    #pragma unroll
    for (int off = 1; off < 64; off <<= 1) pk += __shfl_xor(pk, off);
    if (gt < 128 && (gt & 63) == 0) wred[g * 2 + (gt >> 6)] = pk;
  }
  __syncthreads();

  // ---- stream means for this group's 8 segments into sM ----
  if (g < 2) {
    const int s0g = s0 + g * 8;
    const int tot = wred[g * 2] + wred[g * 2 + 1];
    const int lo = tot >> 10;
    const int hi = tot & 1023;

    const float4* hp = (const float4*)(hidden + (size_t)b * L_ * D_) + gt;
    const uint2 zz = {0u, 0u};

    int cur = (lo < hi) ? sids[lo] : s0g + 8;
    for (int z = s0g; z < cur; ++z)
      *(uint2*)(sM + (z - s0) * 776 + gt * 4) = zz;

    float4 acc = {0.0f, 0.0f, 0.0f, 0.0f};
    int segstart = lo;
    for (int l = lo; l < hi; l += 8) {
      float4 v[8];
      int sv[8];
      #pragma unroll
      for (int k = 0; k < 8; ++k) {
        v[k]  = hp[(size_t)min(l + k, hi - 1) * (D_ / 4)];
        sv[k] = sids[min(l + k + 1, hi - 1)];
      }
      #pragma unroll
      for (int k = 0; k < 8; ++k) {
        if (l + k < hi) {
          acc.x += v[k].x; acc.y += v[k].y;
          acc.z += v[k].z; acc.w += v[k].w;
          const int nx = l + k + 1;
          if (nx == hi || sv[k] != cur) {
            const float inv = 1.0f / (float)(nx - segstart);
            ushort4 h;
            h.x = f2h(acc.x * inv); h.y = f2h(acc.y * inv);
            h.z = f2h(acc.z * inv); h.w = f2h(acc.w * inv);
            *(ushort4*)(sM + (cur - s0) * 776 + gt * 4) = h;
            const int nxt = (nx == hi) ? s0g + 8 : sv[k];
            for (int z = cur + 1; z < nxt; ++z)
              *(uint2*)(sM + (z - s0) * 776 + gt * 4) = zz;
            acc.x = 0.0f; acc.y = 0.0f; acc.z = 0.0f; acc.w = 0.0f;
            segstart = nx; cur = nxt;
          }
        }
      }
    }
  }
  __syncthreads();

  // ---- phase 1: 24 k-tiles, no barriers; wave owns W1 ntiles 3w..3w+2 ----
  f32x4 acc1[3] = {};
  {
    const ushort* bp = w1s + (size_t)(3 * wid) * 24 * 512 + lane * 8;
    #pragma unroll 4
    for (int kt = 0; kt < 24; ++kt) {
      half8 af = *(const half8*)&sM[lrow * 776 + kt * 32 + lk];
      half8 bf[3];
      #pragma unroll
      for (int j = 0; j < 3; ++j)
        bf[j] = *(const half8*)(bp + ((size_t)j * 24 + kt) * 512);
      #pragma unroll
      for (int j = 0; j < 3; ++j)
        acc1[j] = __builtin_amdgcn_mfma_f32_16x16x32_f16(af, bf[j], acc1[j], 0, 0, 0);
    }
  }
  #pragma unroll
  for (int j = 0; j < 3; ++j) {
    const int n = (3 * wid + j) * 16 + lrow;
    const float bj = b1[n];
    #pragma unroll
    for (int r = 0; r < 4; ++r) {
      const int m = (lane >> 4) * 4 + r;
      sH[m * 392 + n] = f2h(fmaxf(acc1[j][r] + bj, 0.0f));
    }
  }
  __syncthreads();

  // ---- phase 2: 12 k-tiles; wave owns W2 ntile = wid ----
  f32x4 a2 = {};
  {
    const ushort* bp = w2s + (size_t)wid * 12 * 512 + lane * 8;
    #pragma unroll 4
    for (int kt = 0; kt < 12; ++kt) {
      half8 af = *(const half8*)&sH[lrow * 392 + kt * 32 + lk];
      half8 bf = *(const half8*)(bp + (size_t)kt * 512);
      a2 = __builtin_amdgcn_mfma_f32_16x16x32_f16(af, bf, a2, 0, 0, 0);
    }
  }

  // ---- epilogue: h2 = relu(a2 + b2); logits = h2 @ W3 + b3 ----
  const int col = wid * 16 + lrow;
  const float w30 = W3[col * 2 + 0];
  const float w31 = W3[col * 2 + 1];
  const float b2v = b2[col];
  #pragma unroll
  for (int r = 0; r < 4; ++r) {
    float v = fmaxf(a2[r] + b2v, 0.0f);
    float p0 = v * w30;
    float p1 = v * w31;
    p0 += __shfl_xor(p0, 1); p1 += __shfl_xor(p1, 1);
    p0 += __shfl_xor(p0, 2); p1 += __shfl_xor(p1, 2);
    p0 += __shfl_xor(p0, 4); p1 += __shfl_xor(p1, 4);
    p0 += __shfl_xor(p0, 8); p1 += __shfl_xor(p1, 8);
    if (lrow == 0) {
      const int row = (lane >> 4) * 4 + r;   // 0..15
      atomicAdd(&pl[row * 2 + 0], p0);
      atomicAdd(&pl[row * 2 + 1], p1);
    }
  }
  __syncthreads();
  if (tid < 32) {
    const int row = tid >> 1, c = tid & 1;
    out[(size_t)(row0 + row) * 2 + c] = pl[tid] + b3[c];
  }
}

// ---------------------------------------------------------------------------
extern "C" void kernel_launch(void* const* d_in, const int* in_sizes, int n_in,
                              void* d_out, int out_size, void* d_ws, size_t ws_size,
                              hipStream_t stream) {
  const float* hidden  = (const float*)d_in[0];
  const int*   seg_ids = (const int*)d_in[1];
  const float* W1 = (const float*)d_in[2];
  const float* b1 = (const float*)d_in[3];
  const float* W2 = (const float*)d_in[4];
  const float* b2 = (const float*)d_in[5];
  const float* W3 = (const float*)d_in[6];
  const float* b3 = (const float*)d_in[7];
  float* out = (float*)d_out;

  char* p = (char*)d_ws;
  ushort* w1s = (ushort*)p;  p += (size_t)N1_ * D_ * 2;     // 0.59 MB swizzled
  ushort* w2s = (ushort*)p;  p += (size_t)N2_ * N1_ * 2;    // 98 KB swizzled

  wswz_kernel<<<32, 192, 0, stream>>>(W1, w1s, W2, w2s);
  fused_all<<<B_ * 4, 512, 0, stream>>>(
      hidden, seg_ids, w1s, b1, w2s, b2, W3, b3, out);
}